// Round 8
// baseline (141.426 us; speedup 1.0000x reference)
//
#include <hip/hip_runtime.h>
#include <hip/hip_bf16.h>

// VectorQuantizer: x [32768 x 64] fp32, e [64 x 1024] fp32.
// d_out = [out (2097152 f32) = x + (q-x), loss = 1.25*mean((q-x)^2)].
//
// R8 = R7 with ONE change: __launch_bounds__(256, 2) on vq_main.
// R7's rocprof showed VGPR_Count=64 (compiler chased max occupancy absent a
// min-waves hint) + 3.5 MB scratch WRITE — spilled loop-carried state inside
// the 32x-barriered K-loop. 2 waves/EU -> 256-VGPR budget; the ~70-reg live
// set allocates clean. Structure: block = 64 rows; wave owns 16 rows x all
// 1024 codes (in-wave butterfly argmin); B (bf16 hi/lo, chunk-XOR swizzle)
// staged 32 codes/tile via global_load_lds into a double buffer; ambiguous
// rows re-scored exactly in fp32 in-block (R1-validated) w/ parallel reduce.

#define NROWS 32768
#define DDIM  64
#define KCODE 1024
#define NELEM (NROWS * DDIM)
#define MARGIN 2.5e-4f
#define NBLK (NROWS / 64)

typedef __attribute__((ext_vector_type(8))) short bf16x8;
typedef __attribute__((ext_vector_type(4))) float f32x4;

static __device__ __forceinline__ unsigned short f2bf(float v) {
    __hip_bfloat16 h = __float2bfloat16(v);
    unsigned short b;
    __builtin_memcpy(&b, &h, 2);
    return b;
}
static __device__ __forceinline__ float bf2f(unsigned short b) {
    unsigned int u = ((unsigned int)b) << 16;
    float f;
    __builtin_memcpy(&f, &u, 4);
    return f;
}
static __device__ __forceinline__ void gload16(const void* g, void* l) {
    __builtin_amdgcn_global_load_lds(
        (const __attribute__((address_space(1))) void*)g,
        (__attribute__((address_space(3))) void*)l, 16, 0, 0);
}

// ---------------------------------------------------------------------------
// prep (64 blocks x 256): per block 16 codes. se[k] exact fp32 (ascending-d
// fmaf — must match recheck), eT[k][d] fp32 (unswizzled), ehT/elT bf16 hi/lo
// with 16B-chunk XOR swizzle: chunk ch of code k stored at slot ch^(k&7).
__global__ void vq_prep(const float* __restrict__ e,
                        float* __restrict__ se,
                        float* __restrict__ eT,
                        unsigned short* __restrict__ ehT,
                        unsigned short* __restrict__ elT,
                        int* __restrict__ ctrl) {
    __shared__ float tile[64][17];
    const int t = threadIdx.x;
    const int k0 = blockIdx.x * 16;
    if (blockIdx.x == 0 && t < 4) ctrl[t] = 0;
    #pragma unroll
    for (int i = 0; i < 4; ++i) {
        int idx = i * 256 + t;
        int d = idx >> 4, kk = idx & 15;
        tile[d][kk] = e[d * KCODE + k0 + kk];
    }
    __syncthreads();
    if (t < 16) {
        float s = 0.f;
        #pragma unroll
        for (int d = 0; d < 64; ++d) { float v = tile[d][t]; s = fmaf(v, v, s); }
        se[k0 + t] = s;
    }
    const int kk = t >> 4;            // code 0..15 within block
    const int dg = (t & 15) * 4;      // dim group (4 elems)
    const int kg = k0 + kk;
    float v0 = tile[dg + 0][kk], v1 = tile[dg + 1][kk];
    float v2 = tile[dg + 2][kk], v3 = tile[dg + 3][kk];
    *(float4*)&eT[(size_t)kg * 64 + dg] = make_float4(v0, v1, v2, v3);
    // swizzled bf16 position: chunk = dg/8 -> slot chunk^(kg&7), keep dg%8
    const int sw = (((dg >> 3) ^ (kg & 7)) << 3) + (dg & 7);
    unsigned short h0 = f2bf(v0), h1 = f2bf(v1), h2 = f2bf(v2), h3 = f2bf(v3);
    *(ushort4*)&ehT[(size_t)kg * 64 + sw] = make_ushort4(h0, h1, h2, h3);
    *(ushort4*)&elT[(size_t)kg * 64 + sw] =
        make_ushort4(f2bf(v0 - bf2f(h0)), f2bf(v1 - bf2f(h1)),
                     f2bf(v2 - bf2f(h2)), f2bf(v3 - bf2f(h3)));
}

// ---------------------------------------------------------------------------
__launch_bounds__(256, 2)
__global__ void vq_main(const float* __restrict__ x,
                        const float* __restrict__ se,
                        const float* __restrict__ eT,
                        const unsigned short* __restrict__ ehT,
                        const unsigned short* __restrict__ elT,
                        float* __restrict__ out,
                        float* __restrict__ lossAcc,
                        int* __restrict__ done) {
    __shared__ unsigned short Bh[2][32 * 64];   // 4 KB per buf
    __shared__ unsigned short Bl[2][32 * 64];
    __shared__ float sse[KCODE];                // 4 KB
    __shared__ int   rowIdx[64];
    __shared__ int   flagRows[64];
    __shared__ int   nFlag;
    __shared__ float xs[64];
    __shared__ float cb[256];
    __shared__ int   ci[256];
    __shared__ float wsum[4];

    const int t = threadIdx.x;
    const int lane = t & 63;
    const int w = t >> 6;                 // wave id 0..3
    const int quad = lane >> 4, l15 = lane & 15;
    const int rowBlk = blockIdx.x * 64;
    const int myRowBase = rowBlk + w * 16;   // wave owns these 16 rows

    if (t == 0) nFlag = 0;

    // ---- stage se into LDS (bit-copy; used by both scan and recheck) ----
    {
        float4 s4 = ((const float4*)se)[t];
        *(float4*)&sse[4 * t] = s4;
    }

    // ---- A fragments for this wave's 16 rows (row = l15, k = quad*8+ks*32+j) ----
    bf16x8 ah[2], al[2];
    #pragma unroll
    for (int ks = 0; ks < 2; ++ks) {
        const float4* ap = (const float4*)(x + (size_t)(myRowBase + l15) * 64
                                           + ks * 32 + quad * 8);
        float4 a0 = ap[0], a1 = ap[1];
        float av[8] = {a0.x, a0.y, a0.z, a0.w, a1.x, a1.y, a1.z, a1.w};
        bf16x8 h, l;
        #pragma unroll
        for (int j = 0; j < 8; ++j) {
            unsigned short hb = f2bf(av[j]);
            h[j] = (short)hb;
            l[j] = (short)f2bf(av[j] - bf2f(hb));
        }
        ah[ks] = h; al[ks] = l;
    }

    // ---- stage tile 0 (32 codes = 4 KB hi + 4 KB lo); wave w fills its 1 KB ----
    {
        const unsigned char* gh = (const unsigned char*)ehT + (size_t)t * 16;
        const unsigned char* gl = (const unsigned char*)elT + (size_t)t * 16;
        gload16(gh, &Bh[0][w * 512]);
        gload16(gl, &Bl[0][w * 512]);
    }
    __syncthreads();   // barrier drains vmcnt -> buffer 0 ready

    float sb[4], sb2[4];
    int   si[4];
    #pragma unroll
    for (int r = 0; r < 4; ++r) { sb[r] = 3.4e38f; sb2[r] = 3.4e38f; si[r] = 0; }

    // swizzled slot bases for this lane's B-frag reads (c&7 == l15&7)
    const int slot0 = ((quad ^ (l15 & 7)) << 3);        // ks=0 chunk
    const int slot1 = (((quad + 4) ^ (l15 & 7)) << 3);  // ks=1 chunk

    for (int tile = 0; tile < 32; ++tile) {
        const int cur = tile & 1;
        if (tile < 31) {   // stage next tile into the other buffer
            const size_t gOff = (size_t)(tile + 1) * 4096 + (size_t)t * 16;
            gload16((const unsigned char*)ehT + gOff, &Bh[cur ^ 1][w * 512]);
            gload16((const unsigned char*)elT + gOff, &Bl[cur ^ 1][w * 512]);
        }
        #pragma unroll
        for (int h = 0; h < 2; ++h) {      // two 16-code subtiles
            const int cloc = h * 16 + l15;             // code within tile
            const int code = tile * 32 + cloc;
            const int cb0  = cloc * 64;
            bf16x8 bh0 = *(const bf16x8*)&Bh[cur][cb0 + slot0];
            bf16x8 bh1 = *(const bf16x8*)&Bh[cur][cb0 + slot1];
            bf16x8 bl0 = *(const bf16x8*)&Bl[cur][cb0 + slot0];
            bf16x8 bl1 = *(const bf16x8*)&Bl[cur][cb0 + slot1];
            float cse = sse[code];
            f32x4 aA = {0.f, 0.f, 0.f, 0.f}, aB = {0.f, 0.f, 0.f, 0.f};
            aA = __builtin_amdgcn_mfma_f32_16x16x32_bf16(ah[0], bh0, aA, 0, 0, 0);
            aB = __builtin_amdgcn_mfma_f32_16x16x32_bf16(ah[1], bh1, aB, 0, 0, 0);
            aA = __builtin_amdgcn_mfma_f32_16x16x32_bf16(ah[0], bl0, aA, 0, 0, 0);
            aB = __builtin_amdgcn_mfma_f32_16x16x32_bf16(ah[1], bl1, aB, 0, 0, 0);
            aA = __builtin_amdgcn_mfma_f32_16x16x32_bf16(al[0], bh0, aA, 0, 0, 0);
            aB = __builtin_amdgcn_mfma_f32_16x16x32_bf16(al[1], bh1, aB, 0, 0, 0);
            #pragma unroll
            for (int r = 0; r < 4; ++r) {
                float key = fmaf(-2.f, aA[r] + aB[r], cse);   // se - 2*dot
                bool lt = key < sb[r];                // strict: earliest code wins
                sb2[r] = fminf(sb2[r], fmaxf(sb[r], key));
                sb[r]  = fminf(sb[r], key);
                si[r]  = lt ? code : si[r];
            }
        }
        __syncthreads();   // compute done everywhere + next-tile loads drained
    }

    // ---- in-wave butterfly argmin over the 16 lanes of each quad ----
    #pragma unroll
    for (int m = 1; m < 16; m <<= 1) {
        #pragma unroll
        for (int r = 0; r < 4; ++r) {
            float ob  = __shfl_xor(sb[r],  m, 64);
            float ob2 = __shfl_xor(sb2[r], m, 64);
            int   oi  = __shfl_xor(si[r],  m, 64);
            float nb2 = fminf(fminf(sb2[r], ob2), fmaxf(sb[r], ob));
            bool take = (ob < sb[r]) || (ob == sb[r] && oi < si[r]);
            sb[r] = take ? ob : sb[r];
            si[r] = take ? oi : si[r];
            sb2[r] = nb2;
        }
    }
    if (l15 == 0) {
        #pragma unroll
        for (int r = 0; r < 4; ++r) {
            const int rl = w * 16 + quad * 4 + r;     // block-local row
            rowIdx[rl] = si[r];
            if (sb2[r] - sb[r] < MARGIN) {
                int p = atomicAdd(&nFlag, 1);
                flagRows[p] = rl;
            }
        }
    }
    __syncthreads();

    // ---- exact fp32 recheck of flagged rows (rare; R1-validated math) ----
    {
        const int nf = nFlag;
        for (int f = 0; f < nf; ++f) {
            const int r = flagRows[f];
            if (t < 64) xs[t] = x[(size_t)(rowBlk + r) * 64 + t];
            __syncthreads();

            float sx = 0.f;
            #pragma unroll
            for (int d = 0; d < 64; ++d) sx = fmaf(xs[d], xs[d], sx);

            float db = 3.4e38f; int di = 0;
            #pragma unroll
            for (int j = 0; j < 4; ++j) {
                int k = t * 4 + j;
                const float4* ep = (const float4*)(eT + (size_t)k * 64);
                float dot = 0.f;
                #pragma unroll 1
                for (int i = 0; i < 16; ++i) {
                    float4 v = ep[i];
                    dot = fmaf(xs[4 * i + 0], v.x, dot);
                    dot = fmaf(xs[4 * i + 1], v.y, dot);
                    dot = fmaf(xs[4 * i + 2], v.z, dot);
                    dot = fmaf(xs[4 * i + 3], v.w, dot);
                }
                float t0 = sx + sse[k];
                float dd = t0 - 2.0f * dot;
                if (dd < db) { db = dd; di = k; }
            }
            cb[t] = db; ci[t] = di;
            __syncthreads();
            if (t < 64) {       // parallel reduce: strided fold + butterfly
                float B = cb[t]; int I = ci[t];
                #pragma unroll
                for (int s = 64; s < 256; s += 64) {
                    float b = cb[t + s]; int i = ci[t + s];
                    bool take = (b < B) || (b == B && i < I);
                    B = take ? b : B;
                    I = take ? i : I;
                }
                #pragma unroll
                for (int m = 1; m < 64; m <<= 1) {
                    float ob = __shfl_xor(B, m, 64);
                    int   oi = __shfl_xor(I, m, 64);
                    bool take = (ob < B) || (ob == B && oi < I);
                    B = take ? ob : B;
                    I = take ? oi : I;
                }
                if (t == 0) rowIdx[r] = I;
            }
            __syncthreads();
        }
    }

    // ---- epilogue: wave w writes rows [w*16, w*16+16); lane: row w*16+l15 ----
    {
        const int rl = w * 16 + l15;
        const int idx = rowIdx[rl];
        const float4* qrow = (const float4*)(eT + (size_t)idx * 64 + quad * 16);
        const float4* xrow = (const float4*)(x + (size_t)(rowBlk + rl) * 64 + quad * 16);
        float4* orow = (float4*)(out + (size_t)(rowBlk + rl) * 64 + quad * 16);
        float lsum = 0.f;
        #pragma unroll
        for (int i = 0; i < 4; ++i) {
            float4 q = qrow[i];
            float4 xv = xrow[i];
            float4 o;
            float dx;
            dx = q.x - xv.x; o.x = xv.x + dx; lsum = fmaf(dx, dx, lsum);
            dx = q.y - xv.y; o.y = xv.y + dx; lsum = fmaf(dx, dx, lsum);
            dx = q.z - xv.z; o.z = xv.z + dx; lsum = fmaf(dx, dx, lsum);
            dx = q.w - xv.w; o.w = xv.w + dx; lsum = fmaf(dx, dx, lsum);
            orow[i] = o;
        }
        #pragma unroll
        for (int off = 32; off > 0; off >>= 1)
            lsum += __shfl_down(lsum, off, 64);
        if (lane == 0) wsum[w] = lsum;
    }
    __syncthreads();

    // ---- block loss add, then atomic-ticket finalize by the last block ----
    if (t == 0) {
        atomicAdd(lossAcc, wsum[0] + wsum[1] + wsum[2] + wsum[3]);
        __threadfence();
        int fin = atomicAdd(done, 1);
        if (fin == NBLK - 1) {
            float s = atomicAdd(lossAcc, 0.0f);   // coherent read of final sum
            float m = s / (float)NELEM;
            out[NELEM] = 0.25f * m + m;
        }
    }
}

// ---------------------------------------------------------------------------
extern "C" void kernel_launch(void* const* d_in, const int* in_sizes, int n_in,
                              void* d_out, int out_size, void* d_ws, size_t ws_size,
                              hipStream_t stream) {
    const float* x = (const float*)d_in[0];
    const float* e = (const float*)d_in[1];
    float* out = (float*)d_out;
    float* ws  = (float*)d_ws;

    // ws layout (float offsets):
    //   [0..15]   ctrl: lossAcc, (unused), done, spare
    //   +64       se   [1024]
    //   +1280     eT   [65536]
    //   +66816    ehT  [65536 ushort = 32768 f]  (swizzled bf16 hi)
    //   +99584    elT  [65536 ushort = 32768 f]  (swizzled bf16 lo)
    float* lossAcc      = ws;
    int*   done         = (int*)(ws + 2);
    float* se           = ws + 64;
    float* eT           = ws + 1280;
    unsigned short* ehT = (unsigned short*)(ws + 66816);
    unsigned short* elT = (unsigned short*)(ws + 99584);

    vq_prep<<<64, 256, 0, stream>>>(e, se, eT, ehT, elT, (int*)ws);
    vq_main<<<NBLK, 256, 0, stream>>>(x, se, eT, ehT, elT, out, lossAcc, done);
}

// Round 9
// 112.378 us; speedup vs baseline: 1.2585x; 1.2585x over previous
//
#include <hip/hip_runtime.h>
#include <hip/hip_bf16.h>

// VectorQuantizer: x [32768 x 64] fp32, e [64 x 1024] fp32.
// d_out = [out (2097152 f32) = x + (q-x), loss = 1.25*mean((q-x)^2)].
//
// R9 = R4's prep + R4's vq_main VERBATIM (empirically the fastest main, ~35us;
// every attempt to touch it in R5-R8 regressed the allocator) + a rewritten
// vq_fix: one block per flagged row, 4 interleaved independent float4 fmaf
// chains per thread (ascending-d per chain == R1-validated exact math), and a
// parallel 256->64 fold + wave-butterfly argmin (R4's serial t==0 reduce was
// ~16us/row; its scalar dependent-load chain another ~8us).

#define NROWS 32768
#define DDIM  64
#define KCODE 1024
#define NELEM (NROWS * DDIM)
#define MARGIN 2.5e-4f
#define FIXBLOCKS 256

typedef __attribute__((ext_vector_type(8))) short bf16x8;
typedef __attribute__((ext_vector_type(4))) float f32x4;

static __device__ __forceinline__ unsigned short f2bf(float v) {
    __hip_bfloat16 h = __float2bfloat16(v);
    unsigned short b;
    __builtin_memcpy(&b, &h, 2);
    return b;
}
static __device__ __forceinline__ float bf2f(unsigned short b) {
    unsigned int u = ((unsigned int)b) << 16;
    float f;
    __builtin_memcpy(&f, &u, 4);
    return f;
}

// ---------------------------------------------------------------------------
// prep (64 blocks x 256): per block 16 codes. se[k] exact fp32 (ascending-d
// fmaf — must match vq_fix), eT[k][d] fp32, ehT/elT[k][d] bf16 hi/lo.
__global__ void vq_prep(const float* __restrict__ e,
                        float* __restrict__ se,
                        float* __restrict__ eT,
                        unsigned short* __restrict__ ehT,
                        unsigned short* __restrict__ elT,
                        int* __restrict__ ctrl) {
    __shared__ float tile[64][17];
    const int t = threadIdx.x;
    const int k0 = blockIdx.x * 16;
    if (blockIdx.x == 0 && t < 4) ctrl[t] = 0;
    #pragma unroll
    for (int i = 0; i < 4; ++i) {
        int idx = i * 256 + t;
        int d = idx >> 4, kk = idx & 15;
        tile[d][kk] = e[d * KCODE + k0 + kk];
    }
    __syncthreads();
    if (t < 16) {
        float s = 0.f;
        #pragma unroll
        for (int d = 0; d < 64; ++d) { float v = tile[d][t]; s = fmaf(v, v, s); }
        se[k0 + t] = s;
    }
    const int kk = t >> 4;           // code 0..15
    const int dg = (t & 15) * 4;     // dim chunk
    float v0 = tile[dg + 0][kk], v1 = tile[dg + 1][kk];
    float v2 = tile[dg + 2][kk], v3 = tile[dg + 3][kk];
    *(float4*)&eT[(size_t)(k0 + kk) * 64 + dg] = make_float4(v0, v1, v2, v3);
    unsigned short h0 = f2bf(v0), h1 = f2bf(v1), h2 = f2bf(v2), h3 = f2bf(v3);
    *(ushort4*)&ehT[(size_t)(k0 + kk) * 64 + dg] = make_ushort4(h0, h1, h2, h3);
    *(ushort4*)&elT[(size_t)(k0 + kk) * 64 + dg] =
        make_ushort4(f2bf(v0 - bf2f(h0)), f2bf(v1 - bf2f(h1)),
                     f2bf(v2 - bf2f(h2)), f2bf(v3 - bf2f(h3)));
}

// ---------------------------------------------------------------------------
// R4's vq_main, verbatim.
__launch_bounds__(256, 2)
__global__ void vq_main(const float* __restrict__ x,
                        const float* __restrict__ se,
                        const float* __restrict__ eT,
                        const unsigned short* __restrict__ ehT,
                        const unsigned short* __restrict__ elT,
                        float* __restrict__ out,
                        float* __restrict__ lossAcc,
                        int* __restrict__ cnt,
                        int2* __restrict__ list) {
    __shared__ float Lb [64][65];
    __shared__ float Lb2[64][65];
    __shared__ int   Li [64][65];
    __shared__ int   rowIdx[64];
    __shared__ float wsum[4];

    const int t = threadIdx.x;
    const int lane = t & 63;
    const int w = t >> 6;                 // 0..3, this wave's K-slice
    const int quad = lane >> 4, l15 = lane & 15;
    const int rowBlk = blockIdx.x * 64;

    // ---- A fragments: 4 M-tiles (rows rowBlk..rowBlk+63), built in-register ----
    bf16x8 ah[4][2], al[4][2];
    #pragma unroll
    for (int mt = 0; mt < 4; ++mt) {
        #pragma unroll
        for (int ks = 0; ks < 2; ++ks) {
            const float4* ap = (const float4*)(x + (size_t)(rowBlk + mt * 16 + l15) * 64
                                               + ks * 32 + quad * 8);
            float4 a0 = ap[0], a1 = ap[1];
            float av[8] = {a0.x, a0.y, a0.z, a0.w, a1.x, a1.y, a1.z, a1.w};
            bf16x8 h, l;
            #pragma unroll
            for (int j = 0; j < 8; ++j) {
                unsigned short hb = f2bf(av[j]);
                h[j] = (short)hb;
                l[j] = (short)f2bf(av[j] - bf2f(hb));
            }
            ah[mt][ks] = h; al[mt][ks] = l;
        }
    }

    float sb[4][4], sb2[4][4];
    int   si[4][4];
    #pragma unroll
    for (int mt = 0; mt < 4; ++mt)
        #pragma unroll
        for (int r = 0; r < 4; ++r) { sb[mt][r] = 3.4e38f; sb2[mt][r] = 3.4e38f; si[mt][r] = 0; }

    // ---- B ring-4 register prefetch over this wave's 256 codes (16 tiles) ----
    const int cbase = w * 256;
    const size_t bStr = (size_t)64;
    bf16x8 h0[4], h1[4], l0[4], l1[4];
    float sen[4];
    #pragma unroll
    for (int p = 0; p < 4; ++p) {
        const int nl = cbase + p * 16 + l15;
        const bf16x8* hp = (const bf16x8*)(ehT + (size_t)nl * bStr + quad * 8);
        const bf16x8* lp = (const bf16x8*)(elT + (size_t)nl * bStr + quad * 8);
        h0[p] = hp[0]; h1[p] = hp[4]; l0[p] = lp[0]; l1[p] = lp[4];
        sen[p] = se[nl];
    }

    #pragma unroll 4
    for (int nt = 0; nt < 16; ++nt) {
        const int p = nt & 3;
        bf16x8 ch0 = h0[p], ch1 = h1[p], cl0 = l0[p], cl1 = l1[p];
        float cse = sen[p];
        {   // prefetch tile nt+4 (reads run into 64-code pad region of ws; never consumed)
            const int nl = cbase + (nt + 4) * 16 + l15;
            const bf16x8* hp = (const bf16x8*)(ehT + (size_t)nl * bStr + quad * 8);
            const bf16x8* lp = (const bf16x8*)(elT + (size_t)nl * bStr + quad * 8);
            h0[p] = hp[0]; h1[p] = hp[4]; l0[p] = lp[0]; l1[p] = lp[4];
            sen[p] = se[nl];
        }
        const int nl = cbase + nt * 16 + l15;
        #pragma unroll
        for (int mt = 0; mt < 4; ++mt) {
            f32x4 aA = {0.f, 0.f, 0.f, 0.f}, aB = {0.f, 0.f, 0.f, 0.f};
            aA = __builtin_amdgcn_mfma_f32_16x16x32_bf16(ah[mt][0], ch0, aA, 0, 0, 0);
            aB = __builtin_amdgcn_mfma_f32_16x16x32_bf16(ah[mt][1], ch1, aB, 0, 0, 0);
            aA = __builtin_amdgcn_mfma_f32_16x16x32_bf16(ah[mt][0], cl0, aA, 0, 0, 0);
            aB = __builtin_amdgcn_mfma_f32_16x16x32_bf16(ah[mt][1], cl1, aB, 0, 0, 0);
            aA = __builtin_amdgcn_mfma_f32_16x16x32_bf16(al[mt][0], ch0, aA, 0, 0, 0);
            aB = __builtin_amdgcn_mfma_f32_16x16x32_bf16(al[mt][1], ch1, aB, 0, 0, 0);
            #pragma unroll
            for (int r = 0; r < 4; ++r) {
                float key = fmaf(-2.f, aA[r] + aB[r], cse);   // se - 2*dot
                bool lt = key < sb[mt][r];                     // strict: earliest k wins
                sb2[mt][r] = fminf(sb2[mt][r], fmaxf(sb[mt][r], key));
                sb[mt][r]  = fminf(sb[mt][r], key);
                si[mt][r]  = lt ? nl : si[mt][r];
            }
        }
    }

    // ---- exchange candidates: row-local = mt*16+quad*4+r, col = w*16+l15 ----
    const int col = w * 16 + l15;
    #pragma unroll
    for (int mt = 0; mt < 4; ++mt)
        #pragma unroll
        for (int r = 0; r < 4; ++r) {
            int rr = mt * 16 + quad * 4 + r;
            Lb [rr][col] = sb [mt][r];
            Lb2[rr][col] = sb2[mt][r];
            Li [rr][col] = si [mt][r];
        }
    __syncthreads();

    // ---- per-row reduce over 64 candidates; flag ambiguous rows ----
    if (t < 64) {
        float B = Lb[t][0], B2 = Lb2[t][0];
        int I = Li[t][0];
        for (int c = 1; c < 64; ++c) {
            float b = Lb[t][c], b2 = Lb2[t][c];
            int i = Li[t][c];
            float nB2 = fminf(fminf(B2, b2), fmaxf(B, b));
            bool take = (b < B) || (b == B && i < I);
            B = take ? b : B;
            I = take ? i : I;
            B2 = nB2;
        }
        rowIdx[t] = I;
        if (B2 - B < MARGIN) {
            int p = atomicAdd(cnt, 1);
            list[p] = make_int2(rowBlk + t, I);
        }
    }
    __syncthreads();

    // ---- epilogue: wave w writes rows [w*16, w*16+16); lane: row w*16+l15 ----
    {
        const int rl = w * 16 + l15;
        const int idx = rowIdx[rl];
        const float4* qrow = (const float4*)(eT + (size_t)idx * 64 + quad * 16);
        const float4* xrow = (const float4*)(x + (size_t)(rowBlk + rl) * 64 + quad * 16);
        float4* orow = (float4*)(out + (size_t)(rowBlk + rl) * 64 + quad * 16);
        float lsum = 0.f;
        #pragma unroll
        for (int i = 0; i < 4; ++i) {
            float4 q = qrow[i];
            float4 xv = xrow[i];
            float4 o;
            float dx;
            dx = q.x - xv.x; o.x = xv.x + dx; lsum = fmaf(dx, dx, lsum);
            dx = q.y - xv.y; o.y = xv.y + dx; lsum = fmaf(dx, dx, lsum);
            dx = q.z - xv.z; o.z = xv.z + dx; lsum = fmaf(dx, dx, lsum);
            dx = q.w - xv.w; o.w = xv.w + dx; lsum = fmaf(dx, dx, lsum);
            orow[i] = o;
        }
        #pragma unroll
        for (int off = 32; off > 0; off >>= 1)
            lsum += __shfl_down(lsum, off, 64);
        if (lane == 0) wsum[w] = lsum;
    }
    __syncthreads();
    if (t == 0)
        atomicAdd(lossAcc, wsum[0] + wsum[1] + wsum[2] + wsum[3]);
}

// ---------------------------------------------------------------------------
// Fast exact fp32 re-score of flagged rows. One block per row (grid-stride).
// Per thread: 4 codes as 4 INTERLEAVED independent fmaf chains (each chain
// ascending-d => bit-identical to R1's validated math). Parallel argmin
// reduce (256 -> 64 fold + wave butterfly). Last block finalizes loss.
__launch_bounds__(256)
__global__ void vq_fix(const float* __restrict__ x,
                       const float* __restrict__ se,
                       const float* __restrict__ eT,
                       const int2* __restrict__ list,
                       const int* __restrict__ cnt,
                       float* __restrict__ lossAcc,
                       int* __restrict__ done,
                       float* __restrict__ out) {
    __shared__ float xs[64];
    __shared__ float cb[256];
    __shared__ int   ci[256];
    __shared__ int   newIdxS;
    const int t = threadIdx.x;
    const int n = *cnt;

    for (int i = blockIdx.x; i < n; i += gridDim.x) {
        int2 en = list[i];
        const int row = en.x, oldIdx = en.y;
        if (t < 64) xs[t] = x[(size_t)row * 64 + t];
        __syncthreads();

        float sx = 0.f;
        #pragma unroll
        for (int d = 0; d < 64; ++d) sx = fmaf(xs[d], xs[d], sx);

        const int k0 = t * 4;
        const float4* e0 = (const float4*)(eT + (size_t)(k0 + 0) * 64);
        const float4* e1 = (const float4*)(eT + (size_t)(k0 + 1) * 64);
        const float4* e2 = (const float4*)(eT + (size_t)(k0 + 2) * 64);
        const float4* e3 = (const float4*)(eT + (size_t)(k0 + 3) * 64);
        float dot0 = 0.f, dot1 = 0.f, dot2 = 0.f, dot3 = 0.f;
        #pragma unroll
        for (int i4 = 0; i4 < 16; ++i4) {
            float4 v0 = e0[i4], v1 = e1[i4], v2 = e2[i4], v3 = e3[i4];
            float xa = xs[4 * i4 + 0], xb = xs[4 * i4 + 1];
            float xc = xs[4 * i4 + 2], xd = xs[4 * i4 + 3];
            dot0 = fmaf(xa, v0.x, dot0); dot0 = fmaf(xb, v0.y, dot0);
            dot0 = fmaf(xc, v0.z, dot0); dot0 = fmaf(xd, v0.w, dot0);
            dot1 = fmaf(xa, v1.x, dot1); dot1 = fmaf(xb, v1.y, dot1);
            dot1 = fmaf(xc, v1.z, dot1); dot1 = fmaf(xd, v1.w, dot1);
            dot2 = fmaf(xa, v2.x, dot2); dot2 = fmaf(xb, v2.y, dot2);
            dot2 = fmaf(xc, v2.z, dot2); dot2 = fmaf(xd, v2.w, dot2);
            dot3 = fmaf(xa, v3.x, dot3); dot3 = fmaf(xb, v3.y, dot3);
            dot3 = fmaf(xc, v3.z, dot3); dot3 = fmaf(xd, v3.w, dot3);
        }
        // dist = (sx + se[k]) - 2*dot, exact ref formula; ascending-k argmin
        float dd0 = (sx + se[k0 + 0]) - 2.0f * dot0;
        float dd1 = (sx + se[k0 + 1]) - 2.0f * dot1;
        float dd2 = (sx + se[k0 + 2]) - 2.0f * dot2;
        float dd3 = (sx + se[k0 + 3]) - 2.0f * dot3;
        float db = dd0; int di = k0;
        if (dd1 < db) { db = dd1; di = k0 + 1; }
        if (dd2 < db) { db = dd2; di = k0 + 2; }
        if (dd3 < db) { db = dd3; di = k0 + 3; }
        cb[t] = db; ci[t] = di;
        __syncthreads();

        if (t < 64) {   // parallel reduce: strided fold + wave butterfly
            float B = cb[t]; int I = ci[t];
            #pragma unroll
            for (int s = 64; s < 256; s += 64) {
                float b = cb[t + s]; int i2 = ci[t + s];
                bool take = (b < B) || (b == B && i2 < I);
                B = take ? b : B;
                I = take ? i2 : I;
            }
            #pragma unroll
            for (int m = 1; m < 64; m <<= 1) {
                float ob = __shfl_xor(B, m, 64);
                int   oi = __shfl_xor(I, m, 64);
                bool take = (ob < B) || (ob == B && oi < I);
                B = take ? ob : B;
                I = take ? oi : I;
            }
            if (t == 0) newIdxS = I;
        }
        __syncthreads();

        const int ni = newIdxS;
        if (ni != oldIdx) {
            if (t < 64) {
                float xv = xs[t];
                float qn = eT[(size_t)ni * 64 + t];
                float qo = eT[(size_t)oldIdx * 64 + t];
                float dn = qn - xv, dl = qo - xv;
                out[(size_t)row * 64 + t] = xv + dn;
                float delta = dn * dn - dl * dl;
                #pragma unroll
                for (int off = 32; off > 0; off >>= 1)
                    delta += __shfl_down(delta, off, 64);
                if (t == 0) atomicAdd(lossAcc, delta);
            }
        }
        __syncthreads();
    }

    if (t == 0) {
        __threadfence();
        int fin = atomicAdd(done, 1);
        if (fin == FIXBLOCKS - 1) {
            float s = atomicAdd(lossAcc, 0.0f);   // coherent read of final sum
            float m = s / (float)NELEM;
            out[NELEM] = 0.25f * m + m;
        }
    }
}

// ---------------------------------------------------------------------------
extern "C" void kernel_launch(void* const* d_in, const int* in_sizes, int n_in,
                              void* d_out, int out_size, void* d_ws, size_t ws_size,
                              hipStream_t stream) {
    const float* x = (const float*)d_in[0];
    const float* e = (const float*)d_in[1];
    float* out = (float*)d_out;
    float* ws  = (float*)d_ws;

    // ws layout (float offsets) — identical to R4:
    //   [0..15]   ctrl: lossAcc, cnt, done, spare
    //   +64       se   [1088 used (64-code read pad); region to +1280]
    //   +1280     eT   [65536]
    //   +66816    ehT  [1088*64 ushort = 34816 f]
    //   +101632   elT  [1088*64 ushort = 34816 f]
    //   +136448   list [32768 int2 = 65536 f]
    float* lossAcc      = ws;
    int*   cnt          = (int*)(ws + 1);
    int*   done         = (int*)(ws + 2);
    float* se           = ws + 64;
    float* eT           = ws + 1280;
    unsigned short* ehT = (unsigned short*)(ws + 66816);
    unsigned short* elT = (unsigned short*)(ws + 101632);
    int2*  list         = (int2*)(ws + 136448);

    vq_prep<<<64, 256, 0, stream>>>(e, se, eT, ehT, elT, (int*)ws);
    vq_main<<<NROWS / 64, 256, 0, stream>>>(x, se, eT, ehT, elT, out, lossAcc, cnt, list);
    vq_fix<<<FIXBLOCKS, 256, 0, stream>>>(x, se, eT, list, cnt, lossAcc, done, out);
}

// Round 10
// 111.908 us; speedup vs baseline: 1.2638x; 1.0042x over previous
//
#include <hip/hip_runtime.h>
#include <hip/hip_bf16.h>

// VectorQuantizer: x [32768 x 64] fp32, e [64 x 1024] fp32.
// d_out = [out (2097152 f32) = x + (q-x), loss = 1.25*mean((q-x)^2)].
//
// R10 = R9 with ONE change: vq_main pinned to exactly 2 waves/EU via
// __attribute__((amdgpu_waves_per_eu(2,2))). History: R3/R5/R7/R8 show the
// allocator ignores the __launch_bounds__ min-waves FLOOR and shrinks VGPRs
// (64/128/64/56) to chase 8 waves/EU, spilling the ~170-reg K-loop live set.
// Pinning min=max=2 grants the 256-VGPR budget and removes the incentive.
// Everything else verbatim: prep; R4 main (ring-4 register prefetch, 6-MFMA
// bf16x3-split, LDS exchange, MARGIN flag list); R9 parallel vq_fix.

#define NROWS 32768
#define DDIM  64
#define KCODE 1024
#define NELEM (NROWS * DDIM)
#define MARGIN 2.5e-4f
#define FIXBLOCKS 256

typedef __attribute__((ext_vector_type(8))) short bf16x8;
typedef __attribute__((ext_vector_type(4))) float f32x4;

static __device__ __forceinline__ unsigned short f2bf(float v) {
    __hip_bfloat16 h = __float2bfloat16(v);
    unsigned short b;
    __builtin_memcpy(&b, &h, 2);
    return b;
}
static __device__ __forceinline__ float bf2f(unsigned short b) {
    unsigned int u = ((unsigned int)b) << 16;
    float f;
    __builtin_memcpy(&f, &u, 4);
    return f;
}

// ---------------------------------------------------------------------------
// prep (64 blocks x 256): per block 16 codes. se[k] exact fp32 (ascending-d
// fmaf — must match vq_fix), eT[k][d] fp32, ehT/elT[k][d] bf16 hi/lo.
__global__ void vq_prep(const float* __restrict__ e,
                        float* __restrict__ se,
                        float* __restrict__ eT,
                        unsigned short* __restrict__ ehT,
                        unsigned short* __restrict__ elT,
                        int* __restrict__ ctrl) {
    __shared__ float tile[64][17];
    const int t = threadIdx.x;
    const int k0 = blockIdx.x * 16;
    if (blockIdx.x == 0 && t < 4) ctrl[t] = 0;
    #pragma unroll
    for (int i = 0; i < 4; ++i) {
        int idx = i * 256 + t;
        int d = idx >> 4, kk = idx & 15;
        tile[d][kk] = e[d * KCODE + k0 + kk];
    }
    __syncthreads();
    if (t < 16) {
        float s = 0.f;
        #pragma unroll
        for (int d = 0; d < 64; ++d) { float v = tile[d][t]; s = fmaf(v, v, s); }
        se[k0 + t] = s;
    }
    const int kk = t >> 4;           // code 0..15
    const int dg = (t & 15) * 4;     // dim chunk
    float v0 = tile[dg + 0][kk], v1 = tile[dg + 1][kk];
    float v2 = tile[dg + 2][kk], v3 = tile[dg + 3][kk];
    *(float4*)&eT[(size_t)(k0 + kk) * 64 + dg] = make_float4(v0, v1, v2, v3);
    unsigned short h0 = f2bf(v0), h1 = f2bf(v1), h2 = f2bf(v2), h3 = f2bf(v3);
    *(ushort4*)&ehT[(size_t)(k0 + kk) * 64 + dg] = make_ushort4(h0, h1, h2, h3);
    *(ushort4*)&elT[(size_t)(k0 + kk) * 64 + dg] =
        make_ushort4(f2bf(v0 - bf2f(h0)), f2bf(v1 - bf2f(h1)),
                     f2bf(v2 - bf2f(h2)), f2bf(v3 - bf2f(h3)));
}

// ---------------------------------------------------------------------------
// R4's vq_main + waves-per-EU pin.
__attribute__((amdgpu_waves_per_eu(2, 2)))
__launch_bounds__(256)
__global__ void vq_main(const float* __restrict__ x,
                        const float* __restrict__ se,
                        const float* __restrict__ eT,
                        const unsigned short* __restrict__ ehT,
                        const unsigned short* __restrict__ elT,
                        float* __restrict__ out,
                        float* __restrict__ lossAcc,
                        int* __restrict__ cnt,
                        int2* __restrict__ list) {
    __shared__ float Lb [64][65];
    __shared__ float Lb2[64][65];
    __shared__ int   Li [64][65];
    __shared__ int   rowIdx[64];
    __shared__ float wsum[4];

    const int t = threadIdx.x;
    const int lane = t & 63;
    const int w = t >> 6;                 // 0..3, this wave's K-slice
    const int quad = lane >> 4, l15 = lane & 15;
    const int rowBlk = blockIdx.x * 64;

    // ---- A fragments: 4 M-tiles (rows rowBlk..rowBlk+63), built in-register ----
    bf16x8 ah[4][2], al[4][2];
    #pragma unroll
    for (int mt = 0; mt < 4; ++mt) {
        #pragma unroll
        for (int ks = 0; ks < 2; ++ks) {
            const float4* ap = (const float4*)(x + (size_t)(rowBlk + mt * 16 + l15) * 64
                                               + ks * 32 + quad * 8);
            float4 a0 = ap[0], a1 = ap[1];
            float av[8] = {a0.x, a0.y, a0.z, a0.w, a1.x, a1.y, a1.z, a1.w};
            bf16x8 h, l;
            #pragma unroll
            for (int j = 0; j < 8; ++j) {
                unsigned short hb = f2bf(av[j]);
                h[j] = (short)hb;
                l[j] = (short)f2bf(av[j] - bf2f(hb));
            }
            ah[mt][ks] = h; al[mt][ks] = l;
        }
    }

    float sb[4][4], sb2[4][4];
    int   si[4][4];
    #pragma unroll
    for (int mt = 0; mt < 4; ++mt)
        #pragma unroll
        for (int r = 0; r < 4; ++r) { sb[mt][r] = 3.4e38f; sb2[mt][r] = 3.4e38f; si[mt][r] = 0; }

    // ---- B ring-4 register prefetch over this wave's 256 codes (16 tiles) ----
    const int cbase = w * 256;
    const size_t bStr = (size_t)64;
    bf16x8 h0[4], h1[4], l0[4], l1[4];
    float sen[4];
    #pragma unroll
    for (int p = 0; p < 4; ++p) {
        const int nl = cbase + p * 16 + l15;
        const bf16x8* hp = (const bf16x8*)(ehT + (size_t)nl * bStr + quad * 8);
        const bf16x8* lp = (const bf16x8*)(elT + (size_t)nl * bStr + quad * 8);
        h0[p] = hp[0]; h1[p] = hp[4]; l0[p] = lp[0]; l1[p] = lp[4];
        sen[p] = se[nl];
    }

    #pragma unroll 4
    for (int nt = 0; nt < 16; ++nt) {
        const int p = nt & 3;
        bf16x8 ch0 = h0[p], ch1 = h1[p], cl0 = l0[p], cl1 = l1[p];
        float cse = sen[p];
        {   // prefetch tile nt+4 (reads run into 64-code pad region of ws; never consumed)
            const int nl = cbase + (nt + 4) * 16 + l15;
            const bf16x8* hp = (const bf16x8*)(ehT + (size_t)nl * bStr + quad * 8);
            const bf16x8* lp = (const bf16x8*)(elT + (size_t)nl * bStr + quad * 8);
            h0[p] = hp[0]; h1[p] = hp[4]; l0[p] = lp[0]; l1[p] = lp[4];
            sen[p] = se[nl];
        }
        const int nl = cbase + nt * 16 + l15;
        #pragma unroll
        for (int mt = 0; mt < 4; ++mt) {
            f32x4 aA = {0.f, 0.f, 0.f, 0.f}, aB = {0.f, 0.f, 0.f, 0.f};
            aA = __builtin_amdgcn_mfma_f32_16x16x32_bf16(ah[mt][0], ch0, aA, 0, 0, 0);
            aB = __builtin_amdgcn_mfma_f32_16x16x32_bf16(ah[mt][1], ch1, aB, 0, 0, 0);
            aA = __builtin_amdgcn_mfma_f32_16x16x32_bf16(ah[mt][0], cl0, aA, 0, 0, 0);
            aB = __builtin_amdgcn_mfma_f32_16x16x32_bf16(ah[mt][1], cl1, aB, 0, 0, 0);
            aA = __builtin_amdgcn_mfma_f32_16x16x32_bf16(al[mt][0], ch0, aA, 0, 0, 0);
            aB = __builtin_amdgcn_mfma_f32_16x16x32_bf16(al[mt][1], ch1, aB, 0, 0, 0);
            #pragma unroll
            for (int r = 0; r < 4; ++r) {
                float key = fmaf(-2.f, aA[r] + aB[r], cse);   // se - 2*dot
                bool lt = key < sb[mt][r];                     // strict: earliest k wins
                sb2[mt][r] = fminf(sb2[mt][r], fmaxf(sb[mt][r], key));
                sb[mt][r]  = fminf(sb[mt][r], key);
                si[mt][r]  = lt ? nl : si[mt][r];
            }
        }
    }

    // ---- exchange candidates: row-local = mt*16+quad*4+r, col = w*16+l15 ----
    const int col = w * 16 + l15;
    #pragma unroll
    for (int mt = 0; mt < 4; ++mt)
        #pragma unroll
        for (int r = 0; r < 4; ++r) {
            int rr = mt * 16 + quad * 4 + r;
            Lb [rr][col] = sb [mt][r];
            Lb2[rr][col] = sb2[mt][r];
            Li [rr][col] = si [mt][r];
        }
    __syncthreads();

    // ---- per-row reduce over 64 candidates; flag ambiguous rows ----
    if (t < 64) {
        float B = Lb[t][0], B2 = Lb2[t][0];
        int I = Li[t][0];
        for (int c = 1; c < 64; ++c) {
            float b = Lb[t][c], b2 = Lb2[t][c];
            int i = Li[t][c];
            float nB2 = fminf(fminf(B2, b2), fmaxf(B, b));
            bool take = (b < B) || (b == B && i < I);
            B = take ? b : B;
            I = take ? i : I;
            B2 = nB2;
        }
        rowIdx[t] = I;
        if (B2 - B < MARGIN) {
            int p = atomicAdd(cnt, 1);
            list[p] = make_int2(rowBlk + t, I);
        }
    }
    __syncthreads();

    // ---- epilogue: wave w writes rows [w*16, w*16+16); lane: row w*16+l15 ----
    {
        const int rl = w * 16 + l15;
        const int idx = rowIdx[rl];
        const float4* qrow = (const float4*)(eT + (size_t)idx * 64 + quad * 16);
        const float4* xrow = (const float4*)(x + (size_t)(rowBlk + rl) * 64 + quad * 16);
        float4* orow = (float4*)(out + (size_t)(rowBlk + rl) * 64 + quad * 16);
        float lsum = 0.f;
        #pragma unroll
        for (int i = 0; i < 4; ++i) {
            float4 q = qrow[i];
            float4 xv = xrow[i];
            float4 o;
            float dx;
            dx = q.x - xv.x; o.x = xv.x + dx; lsum = fmaf(dx, dx, lsum);
            dx = q.y - xv.y; o.y = xv.y + dx; lsum = fmaf(dx, dx, lsum);
            dx = q.z - xv.z; o.z = xv.z + dx; lsum = fmaf(dx, dx, lsum);
            dx = q.w - xv.w; o.w = xv.w + dx; lsum = fmaf(dx, dx, lsum);
            orow[i] = o;
        }
        #pragma unroll
        for (int off = 32; off > 0; off >>= 1)
            lsum += __shfl_down(lsum, off, 64);
        if (lane == 0) wsum[w] = lsum;
    }
    __syncthreads();
    if (t == 0)
        atomicAdd(lossAcc, wsum[0] + wsum[1] + wsum[2] + wsum[3]);
}

// ---------------------------------------------------------------------------
// Fast exact fp32 re-score of flagged rows. One block per row (grid-stride).
// Per thread: 4 codes as 4 INTERLEAVED independent fmaf chains (each chain
// ascending-d => bit-identical to R1's validated math). Parallel argmin
// reduce (256 -> 64 fold + wave butterfly). Last block finalizes loss.
__launch_bounds__(256)
__global__ void vq_fix(const float* __restrict__ x,
                       const float* __restrict__ se,
                       const float* __restrict__ eT,
                       const int2* __restrict__ list,
                       const int* __restrict__ cnt,
                       float* __restrict__ lossAcc,
                       int* __restrict__ done,
                       float* __restrict__ out) {
    __shared__ float xs[64];
    __shared__ float cb[256];
    __shared__ int   ci[256];
    __shared__ int   newIdxS;
    const int t = threadIdx.x;
    const int n = *cnt;

    for (int i = blockIdx.x; i < n; i += gridDim.x) {
        int2 en = list[i];
        const int row = en.x, oldIdx = en.y;
        if (t < 64) xs[t] = x[(size_t)row * 64 + t];
        __syncthreads();

        float sx = 0.f;
        #pragma unroll
        for (int d = 0; d < 64; ++d) sx = fmaf(xs[d], xs[d], sx);

        const int k0 = t * 4;
        const float4* e0 = (const float4*)(eT + (size_t)(k0 + 0) * 64);
        const float4* e1 = (const float4*)(eT + (size_t)(k0 + 1) * 64);
        const float4* e2 = (const float4*)(eT + (size_t)(k0 + 2) * 64);
        const float4* e3 = (const float4*)(eT + (size_t)(k0 + 3) * 64);
        float dot0 = 0.f, dot1 = 0.f, dot2 = 0.f, dot3 = 0.f;
        #pragma unroll
        for (int i4 = 0; i4 < 16; ++i4) {
            float4 v0 = e0[i4], v1 = e1[i4], v2 = e2[i4], v3 = e3[i4];
            float xa = xs[4 * i4 + 0], xb = xs[4 * i4 + 1];
            float xc = xs[4 * i4 + 2], xd = xs[4 * i4 + 3];
            dot0 = fmaf(xa, v0.x, dot0); dot0 = fmaf(xb, v0.y, dot0);
            dot0 = fmaf(xc, v0.z, dot0); dot0 = fmaf(xd, v0.w, dot0);
            dot1 = fmaf(xa, v1.x, dot1); dot1 = fmaf(xb, v1.y, dot1);
            dot1 = fmaf(xc, v1.z, dot1); dot1 = fmaf(xd, v1.w, dot1);
            dot2 = fmaf(xa, v2.x, dot2); dot2 = fmaf(xb, v2.y, dot2);
            dot2 = fmaf(xc, v2.z, dot2); dot2 = fmaf(xd, v2.w, dot2);
            dot3 = fmaf(xa, v3.x, dot3); dot3 = fmaf(xb, v3.y, dot3);
            dot3 = fmaf(xc, v3.z, dot3); dot3 = fmaf(xd, v3.w, dot3);
        }
        // dist = (sx + se[k]) - 2*dot, exact ref formula; ascending-k argmin
        float dd0 = (sx + se[k0 + 0]) - 2.0f * dot0;
        float dd1 = (sx + se[k0 + 1]) - 2.0f * dot1;
        float dd2 = (sx + se[k0 + 2]) - 2.0f * dot2;
        float dd3 = (sx + se[k0 + 3]) - 2.0f * dot3;
        float db = dd0; int di = k0;
        if (dd1 < db) { db = dd1; di = k0 + 1; }
        if (dd2 < db) { db = dd2; di = k0 + 2; }
        if (dd3 < db) { db = dd3; di = k0 + 3; }
        cb[t] = db; ci[t] = di;
        __syncthreads();

        if (t < 64) {   // parallel reduce: strided fold + wave butterfly
            float B = cb[t]; int I = ci[t];
            #pragma unroll
            for (int s = 64; s < 256; s += 64) {
                float b = cb[t + s]; int i2 = ci[t + s];
                bool take = (b < B) || (b == B && i2 < I);
                B = take ? b : B;
                I = take ? i2 : I;
            }
            #pragma unroll
            for (int m = 1; m < 64; m <<= 1) {
                float ob = __shfl_xor(B, m, 64);
                int   oi = __shfl_xor(I, m, 64);
                bool take = (ob < B) || (ob == B && oi < I);
                B = take ? ob : B;
                I = take ? oi : I;
            }
            if (t == 0) newIdxS = I;
        }
        __syncthreads();

        const int ni = newIdxS;
        if (ni != oldIdx) {
            if (t < 64) {
                float xv = xs[t];
                float qn = eT[(size_t)ni * 64 + t];
                float qo = eT[(size_t)oldIdx * 64 + t];
                float dn = qn - xv, dl = qo - xv;
                out[(size_t)row * 64 + t] = xv + dn;
                float delta = dn * dn - dl * dl;
                #pragma unroll
                for (int off = 32; off > 0; off >>= 1)
                    delta += __shfl_down(delta, off, 64);
                if (t == 0) atomicAdd(lossAcc, delta);
            }
        }
        __syncthreads();
    }

    if (t == 0) {
        __threadfence();
        int fin = atomicAdd(done, 1);
        if (fin == FIXBLOCKS - 1) {
            float s = atomicAdd(lossAcc, 0.0f);   // coherent read of final sum
            float m = s / (float)NELEM;
            out[NELEM] = 0.25f * m + m;
        }
    }
}

// ---------------------------------------------------------------------------
extern "C" void kernel_launch(void* const* d_in, const int* in_sizes, int n_in,
                              void* d_out, int out_size, void* d_ws, size_t ws_size,
                              hipStream_t stream) {
    const float* x = (const float*)d_in[0];
    const float* e = (const float*)d_in[1];
    float* out = (float*)d_out;
    float* ws  = (float*)d_ws;

    // ws layout (float offsets) — identical to R4/R9:
    //   [0..15]   ctrl: lossAcc, cnt, done, spare
    //   +64       se   [1088 used (64-code read pad); region to +1280]
    //   +1280     eT   [65536]
    //   +66816    ehT  [1088*64 ushort = 34816 f]
    //   +101632   elT  [1088*64 ushort = 34816 f]
    //   +136448   list [32768 int2 = 65536 f]
    float* lossAcc      = ws;
    int*   cnt          = (int*)(ws + 1);
    int*   done         = (int*)(ws + 2);
    float* se           = ws + 64;
    float* eT           = ws + 1280;
    unsigned short* ehT = (unsigned short*)(ws + 66816);
    unsigned short* elT = (unsigned short*)(ws + 101632);
    int2*  list         = (int2*)(ws + 136448);

    vq_prep<<<64, 256, 0, stream>>>(e, se, eT, ehT, elT, (int*)ws);
    vq_main<<<NROWS / 64, 256, 0, stream>>>(x, se, eT, ehT, elT, out, lossAcc, cnt, list);
    vq_fix<<<FIXBLOCKS, 256, 0, stream>>>(x, se, eT, list, cnt, lossAcc, done, out);
}